// Round 3
// baseline (10390.588 us; speedup 1.0000x reference)
//
#include <hip/hip_runtime.h>
#include <hip/hip_bf16.h>
#include <math.h>

typedef __bf16  bf16x8 __attribute__((ext_vector_type(8)));
typedef float   f32x4  __attribute__((ext_vector_type(4)));
typedef unsigned int uint32;

#define HIDDEN 4096
#define NHQ    32
#define NHKV   8
#define HD     128
#define SEQ    2048
#define BATCH  2
#define NTOK   (BATCH * SEQ)
#define KVDIM  (NHKV * HD)   // 1024

// ---------------------------------------------------------------------------
// Load 8 contiguous elements as bf16, converting from fp32 if needed.
// ---------------------------------------------------------------------------
__device__ inline void load8(const float* p, __bf16* d)
{
    float4 a = *reinterpret_cast<const float4*>(p);
    float4 b = *reinterpret_cast<const float4*>(p + 4);
    d[0] = (__bf16)a.x; d[1] = (__bf16)a.y; d[2] = (__bf16)a.z; d[3] = (__bf16)a.w;
    d[4] = (__bf16)b.x; d[5] = (__bf16)b.y; d[6] = (__bf16)b.z; d[7] = (__bf16)b.w;
}
__device__ inline void load8(const __hip_bfloat16* p, __bf16* d)
{
    *reinterpret_cast<bf16x8*>(d) = *reinterpret_cast<const bf16x8*>(p);
}

__device__ inline void storeC(float* C, size_t idx, float v)          { C[idx] = v; }
__device__ inline void storeC(__hip_bfloat16* C, size_t idx, float v) { C[idx] = __float2bfloat16(v); }

// ---------------------------------------------------------------------------
// GEMM: C = A @ B, A[M][K] (TA), B[K][N] (TB), C (TC: float or bf16).
// Block: 256 thr = 4 waves (2x2), tile BM=64 BN=64 BK=32.
// Each wave: 32x32 quadrant = 2x2 MFMA 16x16x32 tiles.
// Inputs converted to bf16 while staging into LDS (fp32->bf16 fused).
// ---------------------------------------------------------------------------
#define BM 64
#define BN 64
#define BK 32
#define LDSS 40   // padded leading dim (elems); 40*2B=80B => 16B-aligned rows

template <typename TA, typename TB, typename TC>
__global__ __launch_bounds__(256) void gemm_to(
    const TA* __restrict__ A,
    const TB* __restrict__ B,
    TC* __restrict__ C,
    int M, int N, int K)
{
    __shared__ __align__(16) __bf16 As[BM][LDSS];       // As[m][k]
    __shared__ __align__(16) __bf16 Bs[BN][LDSS];       // transposed: Bs[n][k]

    const int tid  = threadIdx.x;
    const int bm   = blockIdx.y * BM;
    const int bn   = blockIdx.x * BN;
    const int wave = tid >> 6;
    const int lane = tid & 63;
    const int wr   = (wave >> 1) * 32;    // wave row offset in tile
    const int wc   = (wave & 1) * 32;     // wave col offset in tile
    const int lrow = lane & 15;
    const int lq   = lane >> 4;           // 0..3

    f32x4 acc[2][2] = {};

    const int ar = tid >> 2;              // 0..63   (A tile row)
    const int ac = (tid & 3) * 8;         // 0..24   (A tile k)
    const int br = tid >> 3;              // 0..31   (B tile k)
    const int bc = (tid & 7) * 8;         // 0..56   (B tile n)

    for (int k0 = 0; k0 < K; k0 += BK) {
        __bf16 abuf[8], bbuf[8];
        load8(A + (size_t)(bm + ar) * K + (k0 + ac), abuf);
        load8(B + (size_t)(k0 + br) * N + (bn + bc), bbuf);

        *reinterpret_cast<bf16x8*>(&As[ar][ac]) = *reinterpret_cast<bf16x8*>(abuf);
        #pragma unroll
        for (int j = 0; j < 8; ++j)
            Bs[bc + j][br] = bbuf[j];

        __syncthreads();

        bf16x8 afrag[2], bfrag[2];
        #pragma unroll
        for (int mi = 0; mi < 2; ++mi)
            afrag[mi] = *reinterpret_cast<const bf16x8*>(&As[wr + mi * 16 + lrow][lq * 8]);
        #pragma unroll
        for (int ni = 0; ni < 2; ++ni)
            bfrag[ni] = *reinterpret_cast<const bf16x8*>(&Bs[wc + ni * 16 + lrow][lq * 8]);

        #pragma unroll
        for (int mi = 0; mi < 2; ++mi)
            #pragma unroll
            for (int ni = 0; ni < 2; ++ni)
                acc[mi][ni] = __builtin_amdgcn_mfma_f32_16x16x32_bf16(
                    afrag[mi], bfrag[ni], acc[mi][ni], 0, 0, 0);

        __syncthreads();
    }

    // Epilogue: D layout col=lane&15, row=(lane>>4)*4+reg
    #pragma unroll
    for (int mi = 0; mi < 2; ++mi)
        #pragma unroll
        for (int ni = 0; ni < 2; ++ni)
            #pragma unroll
            for (int r = 0; r < 4; ++r) {
                int row = bm + wr + mi * 16 + lq * 4 + r;
                int col = bn + wc + ni * 16 + lrow;
                storeC(C, (size_t)row * N + col, acc[mi][ni][r]);
            }
}

// ---------------------------------------------------------------------------
// RoPE in-place on bf16. X layout: [tok][h*HD + d], pairs (i, i+64), i in 0..63.
// ---------------------------------------------------------------------------
__global__ __launch_bounds__(256) void rope_kernel(
    __hip_bfloat16* __restrict__ X, int nh, size_t total)
{
    size_t idx = (size_t)blockIdx.x * blockDim.x + threadIdx.x;
    if (idx >= total) return;
    int    i   = (int)(idx & 63);
    size_t t   = idx >> 6;
    int    h   = (int)(t % nh);
    size_t tok = t / nh;
    int    pos = (int)(tok & (SEQ - 1));

    // inv_freq = 10000^(-i/64) = 2^(-i * log2(10000)/64)
    float inv_freq = exp2f(-(float)i * (13.287712379549449f / 64.0f));
    float fr = (float)pos * inv_freq;
    float sv, cv;
    sincosf(fr, &sv, &cv);

    size_t base = tok * ((size_t)nh * HD) + (size_t)h * HD + i;
    float x1 = __bfloat162float(X[base]);
    float x2 = __bfloat162float(X[base + 64]);
    X[base]      = __float2bfloat16(x1 * cv - x2 * sv);
    X[base + 64] = __float2bfloat16(x2 * cv + x1 * sv);
}

// ---------------------------------------------------------------------------
// Attention: one wave per (b, qh, pos) query row; online softmax over keys
// 0..pos. Lane l owns dims 2l, 2l+1 of D=128. O may alias Q (each wave reads
// only its own q-row into registers before writing its own o-row).
// ---------------------------------------------------------------------------
__device__ inline float2 bf2_to_f2(uint32 u)
{
    union { uint32 i; float f; } a, b;
    a.i = (u & 0xffffu) << 16;
    b.i = u & 0xffff0000u;
    return make_float2(a.f, b.f);
}

__global__ __launch_bounds__(256) void attn_kernel(
    const __hip_bfloat16* __restrict__ Q,
    const __hip_bfloat16* __restrict__ K,
    const __hip_bfloat16* __restrict__ V,
    __hip_bfloat16* __restrict__ O)
{
    const int lane = threadIdx.x & 63;
    const int g    = threadIdx.x >> 6;        // q-head within group
    const int bb   = blockIdx.x;              // [0, BATCH*NHKV*SEQ)
    const int pos  = bb & (SEQ - 1);
    const int kh   = (bb >> 11) & (NHKV - 1);
    const int b    = bb >> 14;
    const int qh   = kh * 4 + g;

    const size_t tok = (size_t)b * SEQ + pos;
    const __hip_bfloat16* qrow  = Q + tok * HIDDEN + (size_t)qh * HD;
    const __hip_bfloat16* Kbase = K + ((size_t)b * SEQ) * KVDIM + (size_t)kh * HD;
    const __hip_bfloat16* Vbase = V + ((size_t)b * SEQ) * KVDIM + (size_t)kh * HD;

    const float SCALE = 0.08838834764831845f;  // 1/sqrt(128)
    float2 qv = bf2_to_f2(*reinterpret_cast<const uint32*>(qrow + 2 * lane));
    qv.x *= SCALE; qv.y *= SCALE;

    float m_run = -INFINITY;
    float l_run = 0.0f;
    float2 acc  = make_float2(0.0f, 0.0f);

    for (int m = 0; m <= pos; ++m) {
        float2 kv2 = bf2_to_f2(*reinterpret_cast<const uint32*>(Kbase + (size_t)m * KVDIM + 2 * lane));
        float2 vv2 = bf2_to_f2(*reinterpret_cast<const uint32*>(Vbase + (size_t)m * KVDIM + 2 * lane));

        float part = qv.x * kv2.x + qv.y * kv2.y;
        #pragma unroll
        for (int off = 32; off; off >>= 1)
            part += __shfl_xor(part, off);

        float mn   = fmaxf(m_run, part);
        float corr = __expf(m_run - mn);   // -inf first iter -> 0
        float p    = __expf(part - mn);
        l_run = l_run * corr + p;
        acc.x = acc.x * corr + p * vv2.x;
        acc.y = acc.y * corr + p * vv2.y;
        m_run = mn;
    }

    float inv = 1.0f / l_run;
    __hip_bfloat16* orow = O + tok * HIDDEN + (size_t)qh * HD;
    orow[2 * lane]     = __float2bfloat16(acc.x * inv);
    orow[2 * lane + 1] = __float2bfloat16(acc.y * inv);
}

// ---------------------------------------------------------------------------
extern "C" void kernel_launch(void* const* d_in, const int* in_sizes, int n_in,
                              void* d_out, int out_size, void* d_ws, size_t ws_size,
                              hipStream_t stream)
{
    // Inputs fp32 (reference dtype). Output fp32 (reference output dtype);
    // the bf16 label in the harness refers only to the tolerance mode.
    const float* x  = (const float*)d_in[0];
    const float* Wq = (const float*)d_in[1];
    const float* Wk = (const float*)d_in[2];
    const float* Wv = (const float*)d_in[3];
    const float* Wo = (const float*)d_in[4];
    float* out = (float*)d_out;

    char* ws = (char*)d_ws;
    __hip_bfloat16* Qb = (__hip_bfloat16*)ws;                                   // NTOK*HIDDEN bf16
    __hip_bfloat16* Kb = (__hip_bfloat16*)(ws + (size_t)NTOK * HIDDEN * 2);     // NTOK*KVDIM
    __hip_bfloat16* Vb = (__hip_bfloat16*)(ws + (size_t)NTOK * HIDDEN * 2
                                              + (size_t)NTOK * KVDIM * 2);      // NTOK*KVDIM

    dim3 blk(256);

    // Projections (fp32 inputs cast to bf16 while staging into LDS)
    gemm_to<float, float, __hip_bfloat16><<<dim3(HIDDEN / BN, NTOK / BM), blk, 0, stream>>>(
        x, Wq, Qb, NTOK, HIDDEN, HIDDEN);
    gemm_to<float, float, __hip_bfloat16><<<dim3(KVDIM / BN, NTOK / BM), blk, 0, stream>>>(
        x, Wk, Kb, NTOK, KVDIM, HIDDEN);
    gemm_to<float, float, __hip_bfloat16><<<dim3(KVDIM / BN, NTOK / BM), blk, 0, stream>>>(
        x, Wv, Vb, NTOK, KVDIM, HIDDEN);

    // RoPE (in place) on Q and K
    {
        size_t totq = (size_t)NTOK * NHQ * 64;
        size_t totk = (size_t)NTOK * NHKV * 64;
        rope_kernel<<<(unsigned)((totq + 255) / 256), blk, 0, stream>>>(Qb, NHQ,  totq);
        rope_kernel<<<(unsigned)((totk + 255) / 256), blk, 0, stream>>>(Kb, NHKV, totk);
    }

    // Attention: O aliases Q buffer (safe: per-wave read-before-write of own row)
    attn_kernel<<<BATCH * NHKV * SEQ, blk, 0, stream>>>(Qb, Kb, Vb, Qb);

    // Output projection: A = bf16 attention out, B = fp32 Wo, C = fp32 out
    gemm_to<__hip_bfloat16, float, float><<<dim3(HIDDEN / BN, NTOK / BM), blk, 0, stream>>>(
        Qb, Wo, out, NTOK, HIDDEN, HIDDEN);
}